// Round 10
// baseline (7828.634 us; speedup 1.0000x reference)
//
#include <hip/hip_runtime.h>

// RNN + FC readout on MI355X — f32 recurrence, quarter-split, R9-PROVEN protocol,
// 2-batch interleave to hide the cross-CU exchange RTT.
//   A: xp[B,T,H] = input @ w_ih^T + b_h   (f32 GEMM; cols 0..255 -> d_out, 256..511 -> d_ws)
//   B: h_t = tanh(xp_t + h_{t-1} @ w_hh^T): 128 blocks = 4/group x 32 groups; each group
//      handles 2 batches, step = [section A][section B], each section == R9's proven
//      protocol verbatim (poll -> barrier -> read -> barrier -> compute -> pacc ->
//      finalize/publish -> barrier -> flag). A's flag RTT hides under B's section.
//      W quarter (128 rows x 512) all-register (128 f32/thread -> AGPRs, proven R9).
//   C: out[B,T,O] = h @ w_out^T + b_out   (f16-dot2 GEMM, f32 in-place over d_out)
//
// f16 W/h in the recurrence refuted (R7: 1.06 — systematic quantization amplifies);
// f16 xp was fine (R5 passed) but phase A/C left f32-proven as-is this round.

typedef _Float16 f16;
typedef __attribute__((ext_vector_type(2))) _Float16 half2_t;
typedef __attribute__((ext_vector_type(4))) float float4_t;

#define NIN    256
#define NHID   512
#define NOUT   256
#define NBATCH 64
#define NT     2048

#define FL4(p) (*reinterpret_cast<const float4_t*>(p))
#define LOADA(p)     __hip_atomic_load((p), __ATOMIC_RELAXED, __HIP_MEMORY_SCOPE_AGENT)
#define STOREA(p, v) __hip_atomic_store((p), (v), __ATOMIC_RELAXED, __HIP_MEMORY_SCOPE_AGENT)

#if __has_builtin(__builtin_amdgcn_fdot2)
__device__ __forceinline__ float fdot2f(half2_t a, half2_t b, float c) {
  return __builtin_amdgcn_fdot2(a, b, c, false);   // v_dot2_f32_f16 (phase C only)
}
#else
__device__ __forceinline__ float fdot2f(half2_t a, half2_t b, float c) {
  return c + (float)a.x * (float)b.x + (float)a.y * (float)b.y;
}
#endif

__device__ float g_hpub[NBATCH][2][NHID];           // h exchange, dbuf by step parity (256 KB)
__device__ __align__(64) int g_flag[NBATCH * 64];   // flag[b*64 + q*16], 64B-padded

__global__ __launch_bounds__(256) void k_zero() {
  g_flag[blockIdx.x * 256 + threadIdx.x] = 0;       // grid 16 -> 4096 ints
}

// ---------------- Phase A: in-projection GEMM, full f32 (proven R5/R6/R9) ----------------
__global__ __launch_bounds__(256) void k_inproj(
    const float* __restrict__ x, const float* __restrict__ w,
    const float* __restrict__ bias, float* __restrict__ xplo, float* __restrict__ xphi)
{
  __shared__ float xs[32][260];
  __shared__ float wsT[8][520];
  const int t = threadIdx.x;
  const int m0 = blockIdx.x * 32;
  const int mthr = t & 3;
  const int nthr = t >> 2;

  #pragma unroll
  for (int r = 0; r < 8; ++r) {
    int f = (t + 256 * r) * 4;
    int row = f >> 8, col = f & 255;
    *(float4_t*)&xs[row][col] =
        *reinterpret_cast<const float4_t*>(x + (size_t)(m0 + row) * NIN + col);
  }

  float acc[8][8];
  #pragma unroll
  for (int nn = 0; nn < 8; ++nn) {
    float bv = bias[nthr * 8 + nn];
    #pragma unroll
    for (int mm = 0; mm < 8; ++mm) acc[nn][mm] = bv;
  }

  for (int kc = 0; kc < 32; ++kc) {
    __syncthreads();
    #pragma unroll
    for (int r = 0; r < 4; ++r) {
      int f = (t + 256 * r) * 4;
      int n = f >> 3, k0 = f & 7;
      float4_t v = *reinterpret_cast<const float4_t*>(w + (size_t)n * NIN + kc * 8 + k0);
      #pragma unroll
      for (int j = 0; j < 4; ++j) wsT[k0 + j][n] = v[j];
    }
    __syncthreads();
    #pragma unroll
    for (int kp = 0; kp < 8; ++kp) {
      float4_t wv0 = *(const float4_t*)&wsT[kp][nthr * 8];
      float4_t wv1 = *(const float4_t*)&wsT[kp][nthr * 8 + 4];
      #pragma unroll
      for (int mm = 0; mm < 8; ++mm) {
        float xv = xs[mthr * 8 + mm][kc * 8 + kp];
        acc[0][mm] = fmaf(wv0.x, xv, acc[0][mm]);
        acc[1][mm] = fmaf(wv0.y, xv, acc[1][mm]);
        acc[2][mm] = fmaf(wv0.z, xv, acc[2][mm]);
        acc[3][mm] = fmaf(wv0.w, xv, acc[3][mm]);
        acc[4][mm] = fmaf(wv1.x, xv, acc[4][mm]);
        acc[5][mm] = fmaf(wv1.y, xv, acc[5][mm]);
        acc[6][mm] = fmaf(wv1.z, xv, acc[6][mm]);
        acc[7][mm] = fmaf(wv1.w, xv, acc[7][mm]);
      }
    }
  }

  const int n0 = nthr * 8;
  float* dst = (n0 < 256) ? (xplo + n0) : (xphi + (n0 - 256));
  #pragma unroll
  for (int mm = 0; mm < 8; ++mm) {
    int m = m0 + mthr * 8 + mm;
    float4_t o0 = {acc[0][mm], acc[1][mm], acc[2][mm], acc[3][mm]};
    float4_t o1 = {acc[4][mm], acc[5][mm], acc[6][mm], acc[7][mm]};
    *reinterpret_cast<float4_t*>(dst + (size_t)m * 256)     = o0;
    *reinterpret_cast<float4_t*>(dst + (size_t)m * 256 + 4) = o1;
  }
}

// ---------------- Phase B: f32 recurrence, quarter-split, 2-batch interleave ----------------
// 128 blocks: xcd=g&7, j=g>>3; q=j&3, group G=xcd+8*(j>>2) in [0,32) -> batches 2G, 2G+1.
// (all 4 blocks of a group share g&7 -> same XCD under round-robin heuristic)
// thread t: js=t&63 -> rows r0=q*128+js*2, r1; ks=t>>6 -> k-slice [ks*64,+64).
// W: w0[16],w1[16] float4 = 128 regs (AGPR-backed, R9-proven). Section protocol == R9.
__global__ __launch_bounds__(512, 1) void k_recur(
    const float* __restrict__ whh, float* outbuf, float* wsbuf)
{
  __shared__ __align__(16) float hbA[2][NHID];
  __shared__ __align__(16) float hbB[2][NHID];
  __shared__ __align__(16) float pacc[8][128];     // shared across sections (non-overlapping)
  const int g = blockIdx.x;
  const int q = (g >> 3) & 3;
  const int G = (g & 7) + 8 * (g >> 5);            // group in [0,32)
  const int bA = 2 * G, bB = 2 * G + 1;
  const int t = threadIdx.x;
  const int js = t & 63;
  const int ks = t >> 6;
  const int r0 = q * 128 + js * 2, r1 = r0 + 1;
  const bool ownk = (ks >> 1) == q;

  float4_t w0[16], w1[16];
  #pragma unroll
  for (int i = 0; i < 16; ++i) {
    w0[i] = FL4(whh + (size_t)r0 * NHID + ks * 64 + i * 4);
    w1[i] = FL4(whh + (size_t)r1 * NHID + ks * 64 + i * 4);
  }

  float* xpA = ((q < 2) ? (outbuf + q * 128) : (wsbuf + (q - 2) * 128))
               + (size_t)bA * NT * 256 + t;        // used by t<128 only
  float* xpB = ((q < 2) ? (outbuf + q * 128) : (wsbuf + (q - 2) * 128))
               + (size_t)bB * NT * 256 + t;
  float xqA0 = 0.f, xqA1 = 0.f, xqB0 = 0.f, xqB1 = 0.f;
  if (t < 128) {
    xqA0 = xpA[0]; xqA1 = xpA[256];
    xqB0 = xpB[0]; xqB1 = xpB[256];
  }

  hbA[0][t] = 0.0f;                                // h_{-1} = 0
  hbB[0][t] = 0.0f;
  __syncthreads();

  // One section == R9's proven per-batch step, verbatim.
  #define SECTION(BB, HB, XP, XQ0, XQ1)                                          \
  {                                                                              \
    float* hbc = HB[s & 1];                                                      \
    float* hbn = HB[(s & 1) ^ 1];                                                \
    float4_t a0 = {0.f,0.f,0.f,0.f}, a1 = {0.f,0.f,0.f,0.f};                     \
    float4_t b0 = {0.f,0.f,0.f,0.f}, b1 = {0.f,0.f,0.f,0.f};                     \
    if (ownk) {                                                                  \
      const float4_t* h4 = (const float4_t*)&hbc[ks * 64];                       \
      _Pragma("unroll")                                                          \
      for (int i = 0; i < 16; i += 2) {                                          \
        float4_t hA = h4[i], hB = h4[i + 1];                                     \
        a0 += w0[i] * hA;  a1 += w0[i + 1] * hB;                                 \
        b0 += w1[i] * hA;  b1 += w1[i + 1] * hB;                                 \
      }                                                                          \
    }                                                                            \
    if (s > 0) {                                                                 \
      if (t < 3) {                                                               \
        const int pq = (q + 1 + t) & 3;                                          \
        while (LOADA(&g_flag[(BB) * 64 + pq * 16]) < s) {}                       \
      }                                                                          \
      __syncthreads();                                                           \
      if (t < 384) {                                                             \
        const int prow = (q * 128 + 128 + t) & 511;                              \
        hbc[prow] = LOADA(&g_hpub[BB][(s - 1) & 1][prow]);                       \
      }                                                                          \
      __syncthreads();                                                           \
    }                                                                            \
    if (!ownk) {                                                                 \
      const float4_t* h4 = (const float4_t*)&hbc[ks * 64];                       \
      _Pragma("unroll")                                                          \
      for (int i = 0; i < 16; i += 2) {                                          \
        float4_t hA = h4[i], hB = h4[i + 1];                                     \
        a0 += w0[i] * hA;  a1 += w0[i + 1] * hB;                                 \
        b0 += w1[i] * hA;  b1 += w1[i + 1] * hB;                                 \
      }                                                                          \
    }                                                                            \
    float4_t av = a0 + a1, bv = b0 + b1;                                         \
    pacc[ks][js * 2]     = (av.x + av.y) + (av.z + av.w);                        \
    pacc[ks][js * 2 + 1] = (bv.x + bv.y) + (bv.z + bv.w);                        \
    __syncthreads();                                                             \
    if (t < 128) {                                                               \
      float sum = pacc[0][t];                                                    \
      _Pragma("unroll")                                                          \
      for (int k2 = 1; k2 < 8; ++k2) sum += pacc[k2][t];                         \
      float h = tanhf(sum + XQ0);                                                \
      hbn[q * 128 + t] = h;                                                      \
      STOREA(&g_hpub[BB][s & 1][q * 128 + t], h);                                \
      (XP)[(size_t)s * 256] = h;                                                 \
      XQ0 = XQ1;                                                                 \
      if (s + 2 < NT) XQ1 = (XP)[(size_t)(s + 2) * 256];                         \
    }                                                                            \
    __syncthreads();                                                             \
    if (t == 0) STOREA(&g_flag[(BB) * 64 + q * 16], s + 1);                      \
  }

  for (int s = 0; s < NT; ++s) {
    SECTION(bA, hbA, xpA, xqA0, xqA1)   // A's flag RTT hides under section B
    SECTION(bB, hbB, xpB, xqB0, xqB1)   // B's flag RTT hides under next step's section A
  }
  #undef SECTION
}

// ---------------- Phase C: out-projection (f16 dot2, f32 out, in-place; proven) ------------
__global__ __launch_bounds__(256) void k_outproj(
    const float* hlo, const float* hhi, const float* __restrict__ w,
    const float* __restrict__ bias, float* out)
{
  __shared__ half2_t xs[32][258];
  __shared__ half2_t ws[256][19];
  const int t = threadIdx.x;
  const int m0 = blockIdx.x * 32;
  const int nthr = t >> 2;
  const int mthr = t & 3;

  #pragma unroll
  for (int r = 0; r < 16; ++r) {
    int f = (t + 256 * r) * 4;
    int row = f >> 9, col = f & 511;
    const float* src = (col < 256) ? (hlo + (size_t)(m0 + row) * 256 + col)
                                   : (hhi + (size_t)(m0 + row) * 256 + (col - 256));
    float4_t v = *reinterpret_cast<const float4_t*>(src);
    xs[row][(col >> 1)]     = half2_t{(f16)v.x, (f16)v.y};
    xs[row][(col >> 1) + 1] = half2_t{(f16)v.z, (f16)v.w};
  }

  float acc[4][8];
  #pragma unroll
  for (int nn = 0; nn < 4; ++nn) {
    float bv = bias[nthr * 4 + nn];
    #pragma unroll
    for (int mm = 0; mm < 8; ++mm) acc[nn][mm] = bv;
  }

  for (int kc = 0; kc < 16; ++kc) {
    __syncthreads();
    #pragma unroll
    for (int r = 0; r < 8; ++r) {
      int f = (t + 256 * r) * 4;
      int row = f >> 5, col = f & 31;
      float4_t v = *reinterpret_cast<const float4_t*>(w + (size_t)row * NHID + kc * 32 + col);
      ws[row][(col >> 1)]     = half2_t{(f16)v.x, (f16)v.y};
      ws[row][(col >> 1) + 1] = half2_t{(f16)v.z, (f16)v.w};
    }
    __syncthreads();
    #pragma unroll
    for (int kp = 0; kp < 16; ++kp) {
      half2_t wv[4], xv[8];
      #pragma unroll
      for (int nn = 0; nn < 4; ++nn) wv[nn] = ws[nthr * 4 + nn][kp];
      #pragma unroll
      for (int mm = 0; mm < 8; ++mm) xv[mm] = xs[mthr * 8 + mm][kc * 16 + kp];
      #pragma unroll
      for (int nn = 0; nn < 4; ++nn)
        #pragma unroll
        for (int mm = 0; mm < 8; ++mm)
          acc[nn][mm] = fdot2f(wv[nn], xv[mm], acc[nn][mm]);
    }
  }

  #pragma unroll
  for (int mm = 0; mm < 8; ++mm) {
    int m = m0 + mthr * 8 + mm;
    float4_t o = {acc[0][mm], acc[1][mm], acc[2][mm], acc[3][mm]};
    *reinterpret_cast<float4_t*>(out + (size_t)m * NOUT + nthr * 4) = o;
  }
}

extern "C" void kernel_launch(void* const* d_in, const int* in_sizes, int n_in,
                              void* d_out, int out_size, void* d_ws, size_t ws_size,
                              hipStream_t stream) {
  (void)in_sizes; (void)n_in; (void)ws_size; (void)out_size;
  const float* x     = (const float*)d_in[0];
  const float* w_ih  = (const float*)d_in[1];
  const float* w_hh  = (const float*)d_in[2];
  const float* b_h   = (const float*)d_in[3];
  const float* w_out = (const float*)d_in[4];
  const float* b_out = (const float*)d_in[5];

  float* outb = (float*)d_out;   // xp cols 0..255  -> h rows 0..255  -> y   (134 MB)
  float* wsb  = (float*)d_ws;    // xp cols 256..511 -> h rows 256..511     (134 MB, proven)

  k_zero   <<<16, 256, 0, stream>>>();
  k_inproj <<<(NBATCH * NT) / 32, 256, 0, stream>>>(x, w_ih, b_h, outb, wsb);
  k_recur  <<<128, 512, 0, stream>>>(w_hh, outb, wsb);
  k_outproj<<<(NBATCH * NT) / 32, 256, 0, stream>>>(outb, wsb, w_out, b_out, outb);
}

// Round 11
// 3926.532 us; speedup vs baseline: 1.9938x; 1.9938x over previous
//
#include <hip/hip_runtime.h>

// RNN + FC readout on MI355X — f32 recurrence, quarter-split, single-RTT tagged exchange.
//   A: xp[B,T,H] = input @ w_ih^T + b_h   (f32 GEMM; cols 0..255 -> d_out, 256..511 -> d_ws)
//   B: h_t = tanh(xp_t + h_{t-1} @ w_hh^T): 256 blocks = 4/batch (R9 grid); W quarter
//      all-register (128 f32/thread, AGPR-backed, proven R9). Exchange: value+tag fused
//      in one u64 (dbuf by step parity) -> poll IS the read (1 LLC RTT, was 2);
//      speculative probe issued before own-k FMAs so the RTT hides under compute.
//      Reduction/buffers: R9-proven pacc-LDS + linear hb (DPP reduce refuted R4/R8).
//   C: out[B,T,O] = h @ w_out^T + b_out   (f16-dot2 GEMM, f32 in-place over d_out)
//
// f16 W/h in recurrence refuted (R7). 2-batch interleave refuted (R10: in-section
// latency, not flag-wait, dominates — sections just serialized).

typedef _Float16 f16;
typedef __attribute__((ext_vector_type(2))) _Float16 half2_t;
typedef __attribute__((ext_vector_type(4))) float float4_t;

#define NIN    256
#define NHID   512
#define NOUT   256
#define NBATCH 64
#define NT     2048

#define FL4(p) (*reinterpret_cast<const float4_t*>(p))
#define LOADA(p)     __hip_atomic_load((p), __ATOMIC_RELAXED, __HIP_MEMORY_SCOPE_AGENT)
#define STOREA(p, v) __hip_atomic_store((p), (v), __ATOMIC_RELAXED, __HIP_MEMORY_SCOPE_AGENT)

#if __has_builtin(__builtin_amdgcn_fdot2)
__device__ __forceinline__ float fdot2f(half2_t a, half2_t b, float c) {
  return __builtin_amdgcn_fdot2(a, b, c, false);   // v_dot2_f32_f16 (phase C only)
}
#else
__device__ __forceinline__ float fdot2f(half2_t a, half2_t b, float c) {
  return c + (float)a.x * (float)b.x + (float)a.y * (float)b.y;
}
#endif

__device__ unsigned long long g_pub[NBATCH][2][NHID];   // (tag s+1)<<32 | f32 bits; 512 KB

__global__ __launch_bounds__(256) void k_zero() {
  ((unsigned long long*)g_pub)[blockIdx.x * 256 + threadIdx.x] = 0ull;   // grid 256
}

// ---------------- Phase A: in-projection GEMM, full f32 (proven R5..R10) ----------------
__global__ __launch_bounds__(256) void k_inproj(
    const float* __restrict__ x, const float* __restrict__ w,
    const float* __restrict__ bias, float* __restrict__ xplo, float* __restrict__ xphi)
{
  __shared__ float xs[32][260];
  __shared__ float wsT[8][520];
  const int t = threadIdx.x;
  const int m0 = blockIdx.x * 32;
  const int mthr = t & 3;
  const int nthr = t >> 2;

  #pragma unroll
  for (int r = 0; r < 8; ++r) {
    int f = (t + 256 * r) * 4;
    int row = f >> 8, col = f & 255;
    *(float4_t*)&xs[row][col] =
        *reinterpret_cast<const float4_t*>(x + (size_t)(m0 + row) * NIN + col);
  }

  float acc[8][8];
  #pragma unroll
  for (int nn = 0; nn < 8; ++nn) {
    float bv = bias[nthr * 8 + nn];
    #pragma unroll
    for (int mm = 0; mm < 8; ++mm) acc[nn][mm] = bv;
  }

  for (int kc = 0; kc < 32; ++kc) {
    __syncthreads();
    #pragma unroll
    for (int r = 0; r < 4; ++r) {
      int f = (t + 256 * r) * 4;
      int n = f >> 3, k0 = f & 7;
      float4_t v = *reinterpret_cast<const float4_t*>(w + (size_t)n * NIN + kc * 8 + k0);
      #pragma unroll
      for (int j = 0; j < 4; ++j) wsT[k0 + j][n] = v[j];
    }
    __syncthreads();
    #pragma unroll
    for (int kp = 0; kp < 8; ++kp) {
      float4_t wv0 = *(const float4_t*)&wsT[kp][nthr * 8];
      float4_t wv1 = *(const float4_t*)&wsT[kp][nthr * 8 + 4];
      #pragma unroll
      for (int mm = 0; mm < 8; ++mm) {
        float xv = xs[mthr * 8 + mm][kc * 8 + kp];
        acc[0][mm] = fmaf(wv0.x, xv, acc[0][mm]);
        acc[1][mm] = fmaf(wv0.y, xv, acc[1][mm]);
        acc[2][mm] = fmaf(wv0.z, xv, acc[2][mm]);
        acc[3][mm] = fmaf(wv0.w, xv, acc[3][mm]);
        acc[4][mm] = fmaf(wv1.x, xv, acc[4][mm]);
        acc[5][mm] = fmaf(wv1.y, xv, acc[5][mm]);
        acc[6][mm] = fmaf(wv1.z, xv, acc[6][mm]);
        acc[7][mm] = fmaf(wv1.w, xv, acc[7][mm]);
      }
    }
  }

  const int n0 = nthr * 8;
  float* dst = (n0 < 256) ? (xplo + n0) : (xphi + (n0 - 256));
  #pragma unroll
  for (int mm = 0; mm < 8; ++mm) {
    int m = m0 + mthr * 8 + mm;
    float4_t o0 = {acc[0][mm], acc[1][mm], acc[2][mm], acc[3][mm]};
    float4_t o1 = {acc[4][mm], acc[5][mm], acc[6][mm], acc[7][mm]};
    *reinterpret_cast<float4_t*>(dst + (size_t)m * 256)     = o0;
    *reinterpret_cast<float4_t*>(dst + (size_t)m * 256 + 4) = o1;
  }
}

// ---------------- Phase B: f32 recurrence, quarter-split, tagged single-RTT exchange -------
// block g: batch b=(g>>5)*8+(g&7), quarter q=(g>>3)&3 owns rows [q*128,+128).
// thread t: js=t&63 -> rows r0=q*128+js*2, r1; ks=t>>6 (wave) -> k-slice [ks*64,+64).
// W: w0[16],w1[16] float4 = 128 regs. pacc-LDS reduction (proven). 3 barriers/step.
__global__ __launch_bounds__(512, 1) void k_recur(
    const float* __restrict__ whh, float* outbuf, float* wsbuf)
{
  __shared__ __align__(16) float hb[2][NHID];
  __shared__ __align__(16) float pacc[8][128];
  const int g = blockIdx.x;
  const int b = (g >> 5) * 8 + (g & 7);
  const int q = (g >> 3) & 3;
  const int t = threadIdx.x;
  const int js = t & 63;
  const int ks = t >> 6;
  const int r0 = q * 128 + js * 2, r1 = r0 + 1;
  const bool ownk = (ks >> 1) == q;
  const int prow = (q * 128 + 128 + t) & 511;       // partner row handled by t (t<384)

  float4_t w0[16], w1[16];
  #pragma unroll
  for (int i = 0; i < 16; ++i) {
    w0[i] = FL4(whh + (size_t)r0 * NHID + ks * 64 + i * 4);
    w1[i] = FL4(whh + (size_t)r1 * NHID + ks * 64 + i * 4);
  }

  float* xp = ((q < 2) ? (outbuf + q * 128) : (wsbuf + (q - 2) * 128))
              + (size_t)b * NT * 256 + t;           // used by t<128 only
  float xq0 = 0.f, xq1 = 0.f;
  if (t < 128) { xq0 = xp[0]; xq1 = xp[256]; }

  hb[0][t] = 0.0f;                                  // h_{-1} = 0
  __syncthreads();

  for (int s = 0; s < NT; ++s) {
    float* hbc = hb[s & 1];
    float* hbn = hb[(s & 1) ^ 1];

    // speculative probe: poll IS the value read (tag rides in high 32 bits)
    const bool rd = (s > 0) && (t < 384);
    unsigned long long pv = 0;
    if (rd) pv = LOADA(&g_pub[b][(s - 1) & 1][prow]);

    float4_t a0 = {0.f,0.f,0.f,0.f}, a1 = {0.f,0.f,0.f,0.f};
    float4_t b0 = {0.f,0.f,0.f,0.f}, b1 = {0.f,0.f,0.f,0.f};
    if (ownk) {                                     // overlaps the probe's LLC RTT
      const float4_t* h4 = (const float4_t*)&hbc[ks * 64];
      #pragma unroll
      for (int i = 0; i < 16; i += 2) {
        float4_t hA = h4[i], hB = h4[i + 1];
        a0 += w0[i] * hA;  a1 += w0[i + 1] * hB;
        b0 += w1[i] * hA;  b1 += w1[i + 1] * hB;
      }
    }

    if (rd) {                                       // spin on residual latency only
      while ((unsigned)(pv >> 32) < (unsigned)s)
        pv = LOADA(&g_pub[b][(s - 1) & 1][prow]);
      hbc[prow] = __builtin_bit_cast(float, (unsigned)pv);
    }
    __syncthreads();                                // full h_{s-1} in hbc

    if (!ownk) {                                    // partner-k (zeros at s==0: correct)
      const float4_t* h4 = (const float4_t*)&hbc[ks * 64];
      #pragma unroll
      for (int i = 0; i < 16; i += 2) {
        float4_t hA = h4[i], hB = h4[i + 1];
        a0 += w0[i] * hA;  a1 += w0[i + 1] * hB;
        b0 += w1[i] * hA;  b1 += w1[i + 1] * hB;
      }
    }

    float4_t av = a0 + a1, bv = b0 + b1;
    pacc[ks][js * 2]     = (av.x + av.y) + (av.z + av.w);
    pacc[ks][js * 2 + 1] = (bv.x + bv.y) + (bv.z + bv.w);
    __syncthreads();                                // pacc complete

    if (t < 128) {                                  // finalize row q*128+t
      float sum = pacc[0][t];
      #pragma unroll
      for (int k2 = 1; k2 < 8; ++k2) sum += pacc[k2][t];
      float h = tanhf(sum + xq0);
      hbn[q * 128 + t] = h;                         // own rows for next step
      STOREA(&g_pub[b][s & 1][q * 128 + t],         // tagged publish (s+1 | bits)
             ((unsigned long long)(unsigned)(s + 1) << 32) |
             (unsigned long long)__builtin_bit_cast(unsigned, h));
      xp[(size_t)s * 256] = h;                      // hs for phase C
      xq0 = xq1;
      if (s + 2 < NT) xq1 = xp[(size_t)(s + 2) * 256];
    }
    __syncthreads();                                // hbn ready; stores drained
  }
}

// ---------------- Phase C: out-projection (f16 dot2, f32 out, in-place; proven) ------------
__global__ __launch_bounds__(256) void k_outproj(
    const float* hlo, const float* hhi, const float* __restrict__ w,
    const float* __restrict__ bias, float* out)
{
  __shared__ half2_t xs[32][258];
  __shared__ half2_t ws[256][19];
  const int t = threadIdx.x;
  const int m0 = blockIdx.x * 32;
  const int nthr = t >> 2;
  const int mthr = t & 3;

  #pragma unroll
  for (int r = 0; r < 16; ++r) {
    int f = (t + 256 * r) * 4;
    int row = f >> 9, col = f & 511;
    const float* src = (col < 256) ? (hlo + (size_t)(m0 + row) * 256 + col)
                                   : (hhi + (size_t)(m0 + row) * 256 + (col - 256));
    float4_t v = *reinterpret_cast<const float4_t*>(src);
    xs[row][(col >> 1)]     = half2_t{(f16)v.x, (f16)v.y};
    xs[row][(col >> 1) + 1] = half2_t{(f16)v.z, (f16)v.w};
  }

  float acc[4][8];
  #pragma unroll
  for (int nn = 0; nn < 4; ++nn) {
    float bv = bias[nthr * 4 + nn];
    #pragma unroll
    for (int mm = 0; mm < 8; ++mm) acc[nn][mm] = bv;
  }

  for (int kc = 0; kc < 16; ++kc) {
    __syncthreads();
    #pragma unroll
    for (int r = 0; r < 8; ++r) {
      int f = (t + 256 * r) * 4;
      int row = f >> 5, col = f & 31;
      float4_t v = *reinterpret_cast<const float4_t*>(w + (size_t)row * NHID + kc * 32 + col);
      ws[row][(col >> 1)]     = half2_t{(f16)v.x, (f16)v.y};
      ws[row][(col >> 1) + 1] = half2_t{(f16)v.z, (f16)v.w};
    }
    __syncthreads();
    #pragma unroll
    for (int kp = 0; kp < 16; ++kp) {
      half2_t wv[4], xv[8];
      #pragma unroll
      for (int nn = 0; nn < 4; ++nn) wv[nn] = ws[nthr * 4 + nn][kp];
      #pragma unroll
      for (int mm = 0; mm < 8; ++mm) xv[mm] = xs[mthr * 8 + mm][kc * 16 + kp];
      #pragma unroll
      for (int nn = 0; nn < 4; ++nn)
        #pragma unroll
        for (int mm = 0; mm < 8; ++mm)
          acc[nn][mm] = fdot2f(wv[nn], xv[mm], acc[nn][mm]);
    }
  }

  #pragma unroll
  for (int mm = 0; mm < 8; ++mm) {
    int m = m0 + mthr * 8 + mm;
    float4_t o = {acc[0][mm], acc[1][mm], acc[2][mm], acc[3][mm]};
    *reinterpret_cast<float4_t*>(out + (size_t)m * NOUT + nthr * 4) = o;
  }
}

extern "C" void kernel_launch(void* const* d_in, const int* in_sizes, int n_in,
                              void* d_out, int out_size, void* d_ws, size_t ws_size,
                              hipStream_t stream) {
  (void)in_sizes; (void)n_in; (void)ws_size; (void)out_size;
  const float* x     = (const float*)d_in[0];
  const float* w_ih  = (const float*)d_in[1];
  const float* w_hh  = (const float*)d_in[2];
  const float* b_h   = (const float*)d_in[3];
  const float* w_out = (const float*)d_in[4];
  const float* b_out = (const float*)d_in[5];

  float* outb = (float*)d_out;   // xp cols 0..255  -> h rows 0..255  -> y   (134 MB)
  float* wsb  = (float*)d_ws;    // xp cols 256..511 -> h rows 256..511     (134 MB, proven)

  k_zero   <<<256, 256, 0, stream>>>();
  k_inproj <<<(NBATCH * NT) / 32, 256, 0, stream>>>(x, w_ih, b_h, outb, wsb);
  k_recur  <<<256, 512, 0, stream>>>(w_hh, outb, wsb);
  k_outproj<<<(NBATCH * NT) / 32, 256, 0, stream>>>(outb, wsb, w_out, b_out, outb);
}

// Round 12
// 3739.965 us; speedup vs baseline: 2.0932x; 1.0499x over previous
//
#include <hip/hip_runtime.h>

// RNN + FC readout on MI355X — f32 recurrence, quarter-split, tagged single-RTT exchange,
// LDS-only (lgkmcnt) barriers in the step loop.
//   A: xp[B,T,H] = input @ w_ih^T + b_h   (f32 GEMM; cols 0..255 -> d_out, 256..511 -> d_ws)
//   B: h_t = tanh(xp_t + h_{t-1} @ w_hh^T): 256 blocks = 4/batch; W quarter all-register
//      (128 f32/thread). Exchange: value+tag fused u64 (dbuf by parity) — poll IS the read.
//      Step-loop barriers are raw `s_waitcnt lgkmcnt(0); s_barrier` — NO vmcnt(0) drain:
//      the xq HBM prefetch spans 2 steps, publish/xp stores are fire-and-forget (tags make
//      visibility self-validating; all cross-thread LDS deps are lgkm-fenced).
//   C: out[B,T,O] = h @ w_out^T + b_out   (f16-dot2 GEMM, f32 in-place over d_out)
//
// R9/R11 carried a hidden ~900cy/step stall: __syncthreads' vmcnt(0) drained the
// finalize-issued HBM prefetch + publish acks at every end-of-step barrier.

typedef _Float16 f16;
typedef __attribute__((ext_vector_type(2))) _Float16 half2_t;
typedef __attribute__((ext_vector_type(4))) float float4_t;

#define NIN    256
#define NHID   512
#define NOUT   256
#define NBATCH 64
#define NT     2048

#define FL4(p) (*reinterpret_cast<const float4_t*>(p))
#define LOADA(p)     __hip_atomic_load((p), __ATOMIC_RELAXED, __HIP_MEMORY_SCOPE_AGENT)
#define STOREA(p, v) __hip_atomic_store((p), (v), __ATOMIC_RELAXED, __HIP_MEMORY_SCOPE_AGENT)

// LDS-only barrier: orders ds ops across the workgroup WITHOUT draining vmcnt.
// sched_barrier(0) pins surrounding code (rule #18: compiler may hoist past inline asm).
#define LDS_BAR() do {                                              \
    asm volatile("s_waitcnt lgkmcnt(0)\n\ts_barrier" ::: "memory"); \
    __builtin_amdgcn_sched_barrier(0);                              \
  } while (0)

#if __has_builtin(__builtin_amdgcn_fdot2)
__device__ __forceinline__ float fdot2f(half2_t a, half2_t b, float c) {
  return __builtin_amdgcn_fdot2(a, b, c, false);   // v_dot2_f32_f16 (phase C only)
}
#else
__device__ __forceinline__ float fdot2f(half2_t a, half2_t b, float c) {
  return c + (float)a.x * (float)b.x + (float)a.y * (float)b.y;
}
#endif

__device__ __forceinline__ float tanh_fast(float x) {   // R5-proven
  float e = __expf(2.0f * x);
  return 1.0f - 2.0f / (e + 1.0f);
}

__device__ unsigned long long g_pub[NBATCH][2][NHID];   // (tag s+1)<<32 | f32 bits; 512 KB

__global__ __launch_bounds__(256) void k_zero() {
  ((unsigned long long*)g_pub)[blockIdx.x * 256 + threadIdx.x] = 0ull;   // grid 256
}

// ---------------- Phase A: in-projection GEMM, full f32 (proven R5..R11) ----------------
__global__ __launch_bounds__(256) void k_inproj(
    const float* __restrict__ x, const float* __restrict__ w,
    const float* __restrict__ bias, float* __restrict__ xplo, float* __restrict__ xphi)
{
  __shared__ float xs[32][260];
  __shared__ float wsT[8][520];
  const int t = threadIdx.x;
  const int m0 = blockIdx.x * 32;
  const int mthr = t & 3;
  const int nthr = t >> 2;

  #pragma unroll
  for (int r = 0; r < 8; ++r) {
    int f = (t + 256 * r) * 4;
    int row = f >> 8, col = f & 255;
    *(float4_t*)&xs[row][col] =
        *reinterpret_cast<const float4_t*>(x + (size_t)(m0 + row) * NIN + col);
  }

  float acc[8][8];
  #pragma unroll
  for (int nn = 0; nn < 8; ++nn) {
    float bv = bias[nthr * 8 + nn];
    #pragma unroll
    for (int mm = 0; mm < 8; ++mm) acc[nn][mm] = bv;
  }

  for (int kc = 0; kc < 32; ++kc) {
    __syncthreads();
    #pragma unroll
    for (int r = 0; r < 4; ++r) {
      int f = (t + 256 * r) * 4;
      int n = f >> 3, k0 = f & 7;
      float4_t v = *reinterpret_cast<const float4_t*>(w + (size_t)n * NIN + kc * 8 + k0);
      #pragma unroll
      for (int j = 0; j < 4; ++j) wsT[k0 + j][n] = v[j];
    }
    __syncthreads();
    #pragma unroll
    for (int kp = 0; kp < 8; ++kp) {
      float4_t wv0 = *(const float4_t*)&wsT[kp][nthr * 8];
      float4_t wv1 = *(const float4_t*)&wsT[kp][nthr * 8 + 4];
      #pragma unroll
      for (int mm = 0; mm < 8; ++mm) {
        float xv = xs[mthr * 8 + mm][kc * 8 + kp];
        acc[0][mm] = fmaf(wv0.x, xv, acc[0][mm]);
        acc[1][mm] = fmaf(wv0.y, xv, acc[1][mm]);
        acc[2][mm] = fmaf(wv0.z, xv, acc[2][mm]);
        acc[3][mm] = fmaf(wv0.w, xv, acc[3][mm]);
        acc[4][mm] = fmaf(wv1.x, xv, acc[4][mm]);
        acc[5][mm] = fmaf(wv1.y, xv, acc[5][mm]);
        acc[6][mm] = fmaf(wv1.z, xv, acc[6][mm]);
        acc[7][mm] = fmaf(wv1.w, xv, acc[7][mm]);
      }
    }
  }

  const int n0 = nthr * 8;
  float* dst = (n0 < 256) ? (xplo + n0) : (xphi + (n0 - 256));
  #pragma unroll
  for (int mm = 0; mm < 8; ++mm) {
    int m = m0 + mthr * 8 + mm;
    float4_t o0 = {acc[0][mm], acc[1][mm], acc[2][mm], acc[3][mm]};
    float4_t o1 = {acc[4][mm], acc[5][mm], acc[6][mm], acc[7][mm]};
    *reinterpret_cast<float4_t*>(dst + (size_t)m * 256)     = o0;
    *reinterpret_cast<float4_t*>(dst + (size_t)m * 256 + 4) = o1;
  }
}

// ---------------- Phase B: f32 recurrence, quarter-split, tagged exchange, LDS barriers ----
// block g: batch b=(g>>5)*8+(g&7), quarter q=(g>>3)&3 owns rows [q*128,+128).
// thread t: js=t&63 -> rows r0=q*128+js*2, r1; ks=t>>6 (wave) -> k-slice [ks*64,+64).
// W: w0[16],w1[16] float4 = 128 regs. pacc-LDS reduction (proven). 3 LDS barriers/step.
__global__ __launch_bounds__(512, 1) void k_recur(
    const float* __restrict__ whh, float* outbuf, float* wsbuf)
{
  __shared__ __align__(16) float hb[2][NHID];
  __shared__ __align__(16) float pacc[8][128];
  const int g = blockIdx.x;
  const int b = (g >> 5) * 8 + (g & 7);
  const int q = (g >> 3) & 3;
  const int t = threadIdx.x;
  const int js = t & 63;
  const int ks = t >> 6;
  const int r0 = q * 128 + js * 2, r1 = r0 + 1;
  const bool ownk = (ks >> 1) == q;
  const int prow = (q * 128 + 128 + t) & 511;       // partner row handled by t (t<384)

  float4_t w0[16], w1[16];
  #pragma unroll
  for (int i = 0; i < 16; ++i) {
    w0[i] = FL4(whh + (size_t)r0 * NHID + ks * 64 + i * 4);
    w1[i] = FL4(whh + (size_t)r1 * NHID + ks * 64 + i * 4);
  }

  float* xp = ((q < 2) ? (outbuf + q * 128) : (wsbuf + (q - 2) * 128))
              + (size_t)b * NT * 256 + t;           // used by t<128 only
  float xq0 = 0.f, xq1 = 0.f;
  if (t < 128) { xq0 = xp[0]; xq1 = xp[256]; }

  hb[0][t] = 0.0f;                                  // h_{-1} = 0
  __syncthreads();                                  // prologue: full drain once, fine

  for (int s = 0; s < NT; ++s) {
    float* hbc = hb[s & 1];
    float* hbn = hb[(s & 1) ^ 1];

    // speculative probe: poll IS the value read (tag rides in high 32 bits)
    const bool rd = (s > 0) && (t < 384);
    unsigned long long pv = 0;
    if (rd) pv = LOADA(&g_pub[b][(s - 1) & 1][prow]);

    float4_t a0 = {0.f,0.f,0.f,0.f}, a1 = {0.f,0.f,0.f,0.f};
    float4_t b0 = {0.f,0.f,0.f,0.f}, b1 = {0.f,0.f,0.f,0.f};
    if (ownk) {                                     // overlaps the probe's LLC RTT
      const float4_t* h4 = (const float4_t*)&hbc[ks * 64];
      #pragma unroll
      for (int i = 0; i < 16; i += 2) {
        float4_t hA = h4[i], hB = h4[i + 1];
        a0 += w0[i] * hA;  a1 += w0[i + 1] * hB;
        b0 += w1[i] * hA;  b1 += w1[i + 1] * hB;
      }
    }

    if (rd) {                                       // spin on residual latency only
      while ((unsigned)(pv >> 32) < (unsigned)s)
        pv = LOADA(&g_pub[b][(s - 1) & 1][prow]);
      hbc[prow] = __builtin_bit_cast(float, (unsigned)pv);
    }
    LDS_BAR();                                      // full h_{s-1} in hbc (ds-order only)

    if (!ownk) {                                    // partner-k (zeros at s==0: correct)
      const float4_t* h4 = (const float4_t*)&hbc[ks * 64];
      #pragma unroll
      for (int i = 0; i < 16; i += 2) {
        float4_t hA = h4[i], hB = h4[i + 1];
        a0 += w0[i] * hA;  a1 += w0[i + 1] * hB;
        b0 += w1[i] * hA;  b1 += w1[i + 1] * hB;
      }
    }

    float4_t av = a0 + a1, bv = b0 + b1;
    pacc[ks][js * 2]     = (av.x + av.y) + (av.z + av.w);
    pacc[ks][js * 2 + 1] = (bv.x + bv.y) + (bv.z + bv.w);
    LDS_BAR();                                      // pacc complete

    if (t < 128) {                                  // finalize row q*128+t
      float sum = pacc[0][t];
      #pragma unroll
      for (int k2 = 1; k2 < 8; ++k2) sum += pacc[k2][t];
      float h = tanh_fast(sum + xq0);
      STOREA(&g_pub[b][s & 1][q * 128 + t],         // publish first: peers see ASAP
             ((unsigned long long)(unsigned)(s + 1) << 32) |
             (unsigned long long)__builtin_bit_cast(unsigned, h));
      hbn[q * 128 + t] = h;                         // own rows for next step
      xp[(size_t)s * 256] = h;                      // hs for phase C (fire-and-forget)
      xq0 = xq1;                                    // vmcnt wait auto-inserted here (hidden)
      if (s + 2 < NT) xq1 = xp[(size_t)(s + 2) * 256];   // spans 2 steps, never drained
    }
    LDS_BAR();                                      // hbn ready (ds-order only)
  }
}

// ---------------- Phase C: out-projection (f16 dot2, f32 out, in-place; proven) ------------
__global__ __launch_bounds__(256) void k_outproj(
    const float* hlo, const float* hhi, const float* __restrict__ w,
    const float* __restrict__ bias, float* out)
{
  __shared__ half2_t xs[32][258];
  __shared__ half2_t ws[256][19];
  const int t = threadIdx.x;
  const int m0 = blockIdx.x * 32;
  const int nthr = t >> 2;
  const int mthr = t & 3;

  #pragma unroll
  for (int r = 0; r < 16; ++r) {
    int f = (t + 256 * r) * 4;
    int row = f >> 9, col = f & 511;
    const float* src = (col < 256) ? (hlo + (size_t)(m0 + row) * 256 + col)
                                   : (hhi + (size_t)(m0 + row) * 256 + (col - 256));
    float4_t v = *reinterpret_cast<const float4_t*>(src);
    xs[row][(col >> 1)]     = half2_t{(f16)v.x, (f16)v.y};
    xs[row][(col >> 1) + 1] = half2_t{(f16)v.z, (f16)v.w};
  }

  float acc[4][8];
  #pragma unroll
  for (int nn = 0; nn < 4; ++nn) {
    float bv = bias[nthr * 4 + nn];
    #pragma unroll
    for (int mm = 0; mm < 8; ++mm) acc[nn][mm] = bv;
  }

  for (int kc = 0; kc < 16; ++kc) {
    __syncthreads();
    #pragma unroll
    for (int r = 0; r < 8; ++r) {
      int f = (t + 256 * r) * 4;
      int row = f >> 5, col = f & 31;
      float4_t v = *reinterpret_cast<const float4_t*>(w + (size_t)row * NHID + kc * 32 + col);
      ws[row][(col >> 1)]     = half2_t{(f16)v.x, (f16)v.y};
      ws[row][(col >> 1) + 1] = half2_t{(f16)v.z, (f16)v.w};
    }
    __syncthreads();
    #pragma unroll
    for (int kp = 0; kp < 16; ++kp) {
      half2_t wv[4], xv[8];
      #pragma unroll
      for (int nn = 0; nn < 4; ++nn) wv[nn] = ws[nthr * 4 + nn][kp];
      #pragma unroll
      for (int mm = 0; mm < 8; ++mm) xv[mm] = xs[mthr * 8 + mm][kc * 16 + kp];
      #pragma unroll
      for (int nn = 0; nn < 4; ++nn)
        #pragma unroll
        for (int mm = 0; mm < 8; ++mm)
          acc[nn][mm] = fdot2f(wv[nn], xv[mm], acc[nn][mm]);
    }
  }

  #pragma unroll
  for (int mm = 0; mm < 8; ++mm) {
    int m = m0 + mthr * 8 + mm;
    float4_t o = {acc[0][mm], acc[1][mm], acc[2][mm], acc[3][mm]};
    *reinterpret_cast<float4_t*>(out + (size_t)m * NOUT + nthr * 4) = o;
  }
}

extern "C" void kernel_launch(void* const* d_in, const int* in_sizes, int n_in,
                              void* d_out, int out_size, void* d_ws, size_t ws_size,
                              hipStream_t stream) {
  (void)in_sizes; (void)n_in; (void)ws_size; (void)out_size;
  const float* x     = (const float*)d_in[0];
  const float* w_ih  = (const float*)d_in[1];
  const float* w_hh  = (const float*)d_in[2];
  const float* b_h   = (const float*)d_in[3];
  const float* w_out = (const float*)d_in[4];
  const float* b_out = (const float*)d_in[5];

  float* outb = (float*)d_out;   // xp cols 0..255  -> h rows 0..255  -> y   (134 MB)
  float* wsb  = (float*)d_ws;    // xp cols 256..511 -> h rows 256..511     (134 MB, proven)

  k_zero   <<<256, 256, 0, stream>>>();
  k_inproj <<<(NBATCH * NT) / 32, 256, 0, stream>>>(x, w_ih, b_h, outb, wsb);
  k_recur  <<<256, 512, 0, stream>>>(w_hh, outb, wsb);
  k_outproj<<<(NBATCH * NT) / 32, 256, 0, stream>>>(outb, wsb, w_out, b_out, outb);
}